// Round 1
// baseline (347.232 us; speedup 1.0000x reference)
//
#include <hip/hip_runtime.h>

// ---------- types ----------
typedef unsigned short u16;
typedef __attribute__((ext_vector_type(4))) float f32x4;
typedef __attribute__((ext_vector_type(8))) short s16x8;
typedef __attribute__((ext_vector_type(8))) __bf16 bf16x8;
typedef __attribute__((ext_vector_type(4))) unsigned short u16x4;

#define LOG2E 1.44269504088896340736f

__device__ __forceinline__ u16 f2bf(float f) {
  unsigned u = __builtin_bit_cast(unsigned, f);
  u += 0x7fffu + ((u >> 16) & 1u);  // RNE
  return (u16)(u >> 16);
}

__device__ __forceinline__ f32x4 mfma16(s16x8 a, s16x8 b, f32x4 c) {
  return __builtin_amdgcn_mfma_f32_16x16x32_bf16(
      __builtin_bit_cast(bf16x8, a), __builtin_bit_cast(bf16x8, b), c, 0, 0, 0);
}

// global -> LDS direct copy, 16B per lane. LDS dest must be uniform-base + lane*16.
#define GLOAD_LDS16(g, l)                                                      \
  __builtin_amdgcn_global_load_lds(                                            \
      (const __attribute__((address_space(1))) unsigned int*)(g),              \
      (__attribute__((address_space(3))) unsigned int*)(l), 16, 0, 0)

// ---------- cast x f32 -> bf16 (4 elems/thread, exact grid) ----------
__global__ __launch_bounds__(256) void k_cast_bf16(const float* __restrict__ in,
                                                   u16* __restrict__ out) {
  int i = (blockIdx.x * 256 + threadIdx.x) * 4;
  float4 v = *(const float4*)(in + i);
  u16x4 o = {f2bf(v.x), f2bf(v.y), f2bf(v.z), f2bf(v.w)};
  *(u16x4*)(out + i) = o;
}

// ---------- Wq/Wk/Wv [H,C,D] f32 -> Wt [3*H*D][C] bf16 (B^T layout) ----------
// Wt[qkv*1024 + h*64 + d][c] = W{qkv}[h][c][d]
__global__ __launch_bounds__(256) void k_wqkv(const float* __restrict__ Wq,
                                              const float* __restrict__ Wk,
                                              const float* __restrict__ Wv,
                                              u16* __restrict__ Wt) {
  int z = blockIdx.y;  // 0..47
  int qkv = z >> 4, h = z & 15;
  const float* in = (qkv == 0 ? Wq : (qkv == 1 ? Wk : Wv)) + h * 1024 * 64;
  int c0 = blockIdx.x * 64;
  __shared__ float tile[64][65];
  int t = threadIdx.x;
  int rA = t >> 4, cA = (t & 15) * 4;
#pragma unroll
  for (int rr = 0; rr < 4; ++rr) {
    int c = rr * 16 + rA;
    float4 v = *(const float4*)(in + (c0 + c) * 64 + cA);
    tile[c][cA] = v.x; tile[c][cA + 1] = v.y; tile[c][cA + 2] = v.z; tile[c][cA + 3] = v.w;
  }
  __syncthreads();
  int obase = qkv * 1024 + h * 64;
#pragma unroll
  for (int rr = 0; rr < 4; ++rr) {
    int d = rr * 16 + rA;
    u16x4 o = {f2bf(tile[cA][d]), f2bf(tile[cA + 1][d]), f2bf(tile[cA + 2][d]),
               f2bf(tile[cA + 3][d])};
    *(u16x4*)(Wt + (obase + d) * 1024 + c0 + cA) = o;
  }
}

// ---------- Wp [1024][1024] f32 -> WpT [n][k] bf16 ----------
__global__ __launch_bounds__(256) void k_wp(const float* __restrict__ in,
                                            u16* __restrict__ out) {
  int r0 = blockIdx.y * 64, c0 = blockIdx.x * 64;
  __shared__ float tile[64][65];
  int t = threadIdx.x;
  int rA = t >> 4, cA = (t & 15) * 4;
#pragma unroll
  for (int rr = 0; rr < 4; ++rr) {
    int r = rr * 16 + rA;
    float4 v = *(const float4*)(in + (r0 + r) * 1024 + c0 + cA);
    tile[r][cA] = v.x; tile[r][cA + 1] = v.y; tile[r][cA + 2] = v.z; tile[r][cA + 3] = v.w;
  }
  __syncthreads();
#pragma unroll
  for (int rr = 0; rr < 4; ++rr) {
    int c = rr * 16 + rA;
    u16x4 o = {f2bf(tile[cA][c]), f2bf(tile[cA + 1][c]), f2bf(tile[cA + 2][c]),
               f2bf(tile[cA + 3][c])};
    *(u16x4*)(out + (c0 + c) * 1024 + r0 + cA) = o;
  }
}

// ---------- GEMM: C[M,N] = A[M,K] @ Bt[N,K]^T  (bf16 in, f32 acc) ----------
// 128x128 tile, BK=64, 4 waves (each 64x64 = 4x4 frags of 16x16x32)
template <int F32OUT>
__global__ __launch_bounds__(256) void gemm_bt(const u16* __restrict__ A,
                                               const u16* __restrict__ Bt,
                                               u16* __restrict__ Cb,
                                               float* __restrict__ Cf,
                                               const float* __restrict__ bias,
                                               int M, int N, int K) {
  __shared__ alignas(16) u16 As[128 * 64];
  __shared__ alignas(16) u16 Bs[128 * 64];
  const int tid = threadIdx.x;
  const int lane = tid & 63, w = tid >> 6;
  const int wr = w >> 1, wc = w & 1;
  const int g = lane >> 4, c15 = lane & 15;
  const int nbk = N >> 7;
  const int bm = blockIdx.x / nbk, bn = blockIdx.x % nbk;

  f32x4 acc[4][4] = {};

  const int srow = tid >> 3;        // 0..31 (+ i*32)
  const int scol = (tid & 7) * 8;   // 0..56
  const u16* Ag = A + (bm * 128 + srow) * K + scol;
  const u16* Bg = Bt + (bn * 128 + srow) * K + scol;
  const int lds_e = tid * 8;        // + i*2048

  for (int kt = 0; kt < K; kt += 64) {
#pragma unroll
    for (int i = 0; i < 4; ++i) GLOAD_LDS16(Ag + i * 32 * K + kt, &As[lds_e + i * 2048]);
#pragma unroll
    for (int i = 0; i < 4; ++i) GLOAD_LDS16(Bg + i * 32 * K + kt, &Bs[lds_e + i * 2048]);
    __syncthreads();
#pragma unroll
    for (int kc = 0; kc < 2; ++kc) {
      s16x8 a[4], b[4];
#pragma unroll
      for (int mb = 0; mb < 4; ++mb)
        a[mb] = *(const s16x8*)&As[(wr * 64 + mb * 16 + c15) * 64 + kc * 32 + g * 8];
#pragma unroll
      for (int nb = 0; nb < 4; ++nb)
        b[nb] = *(const s16x8*)&Bs[(wc * 64 + nb * 16 + c15) * 64 + kc * 32 + g * 8];
#pragma unroll
      for (int mb = 0; mb < 4; ++mb)
#pragma unroll
        for (int nb = 0; nb < 4; ++nb) acc[mb][nb] = mfma16(a[mb], b[nb], acc[mb][nb]);
    }
    __syncthreads();
  }
#pragma unroll
  for (int mb = 0; mb < 4; ++mb) {
#pragma unroll
    for (int nb = 0; nb < 4; ++nb) {
      int row0 = bm * 128 + wr * 64 + mb * 16 + g * 4;
      int col = bn * 128 + wc * 64 + nb * 16 + c15;
#pragma unroll
      for (int r = 0; r < 4; ++r) {
        float v = acc[mb][nb][r];
        if (F32OUT)
          Cf[(row0 + r) * N + col] = v + bias[col];
        else
          Cb[(row0 + r) * N + col] = f2bf(v);
      }
    }
  }
}

// ---------- flash attention ----------
// QKV [4096][3072] bf16 (row = b*2048+t, col = qkv*1024 + h*64 + d)
// AO: torch-raw-reshape layout: AO[(2h+b)*131072 + t*64 + d]  (as [4096][1024])
__global__ __launch_bounds__(256) void attn_fwd(const u16* __restrict__ QKV,
                                                u16* __restrict__ AO) {
  __shared__ alignas(16) u16 Ks[64 * 64];      // [key][d]
  __shared__ alignas(16) u16 Vt[64 * 64];      // [d][key]
  __shared__ alignas(16) u16 Ps[4][64 * 64];   // per-wave P [q][key]
  const int tid = threadIdx.x, lane = tid & 63, w = tid >> 6;
  const int qb = blockIdx.x;       // 0..7
  const int bh = blockIdx.y;       // 0..31
  const int h = bh >> 1, b = bh & 1;
  const int g = lane >> 4, c15 = lane & 15;
  const int bt0 = b * 2048;

  // Q fragments (pre-loaded, stay in regs): rows qb*256 + w*64 + mb*16 + c15
  s16x8 q[4][2];
#pragma unroll
  for (int mb = 0; mb < 4; ++mb)
#pragma unroll
    for (int kc = 0; kc < 2; ++kc) {
      int row = bt0 + qb * 256 + w * 64 + mb * 16 + c15;
      q[mb][kc] = *(const s16x8*)&QKV[row * 3072 + h * 64 + kc * 32 + g * 8];
    }

  f32x4 o[4][4] = {};
  float mrow[4][4], lrow[4][4];
#pragma unroll
  for (int mb = 0; mb < 4; ++mb)
#pragma unroll
    for (int r = 0; r < 4; ++r) { mrow[mb][r] = -1e30f; lrow[mb][r] = 0.f; }

  const int skey = tid >> 3;       // 0..31 (+ i*32)
  const int sd0 = (tid & 7) * 8;
  const u16* Kg = QKV + (bt0 + skey) * 3072 + 1024 + h * 64 + sd0;
  const u16* Vg = QKV + (bt0 + skey) * 3072 + 2048 + h * 64 + sd0;

  for (int key0 = 0; key0 < 2048; key0 += 64) {
    // stage K tile -> LDS (direct)
#pragma unroll
    for (int i = 0; i < 2; ++i)
      GLOAD_LDS16(Kg + (key0 + i * 32) * 3072, &Ks[tid * 8 + i * 2048]);
    // stage V tile transposed via registers
#pragma unroll
    for (int i = 0; i < 2; ++i) {
      s16x8 v = *(const s16x8*)(Vg + (key0 + i * 32) * 3072);
      int key = skey + i * 32;
#pragma unroll
      for (int j = 0; j < 8; ++j) Vt[(sd0 + j) * 64 + key] = (u16)v[j];
    }
    __syncthreads();

    // S = Q K^T (scaled later)
    f32x4 s[4][4] = {};
#pragma unroll
    for (int kc = 0; kc < 2; ++kc) {
      s16x8 kf[4];
#pragma unroll
      for (int nb = 0; nb < 4; ++nb)
        kf[nb] = *(const s16x8*)&Ks[(nb * 16 + c15) * 64 + kc * 32 + g * 8];
#pragma unroll
      for (int mb = 0; mb < 4; ++mb)
#pragma unroll
        for (int nb = 0; nb < 4; ++nb) s[mb][nb] = mfma16(q[mb][kc], kf[nb], s[mb][nb]);
    }

    // online softmax (wave-parallel: rows live on 16-lane groups)
#pragma unroll
    for (int mb = 0; mb < 4; ++mb) {
#pragma unroll
      for (int r = 0; r < 4; ++r) {
        float mx = -1e30f;
#pragma unroll
        for (int nb = 0; nb < 4; ++nb) {
          s[mb][nb][r] *= 0.125f;
          mx = fmaxf(mx, s[mb][nb][r]);
        }
#pragma unroll
        for (int off = 8; off >= 1; off >>= 1) mx = fmaxf(mx, __shfl_xor(mx, off, 64));
        float mo = mrow[mb][r];
        float mn = fmaxf(mo, mx);
        float alpha = exp2f((mo - mn) * LOG2E);
        mrow[mb][r] = mn;
        float rs = 0.f;
#pragma unroll
        for (int nb = 0; nb < 4; ++nb) {
          float p = exp2f((s[mb][nb][r] - mn) * LOG2E);
          s[mb][nb][r] = p;
          rs += p;
        }
#pragma unroll
        for (int off = 8; off >= 1; off >>= 1) rs += __shfl_xor(rs, off, 64);
        lrow[mb][r] = lrow[mb][r] * alpha + rs;
#pragma unroll
        for (int db = 0; db < 4; ++db) o[mb][db][r] *= alpha;
      }
    }

    // P -> per-wave LDS (bf16)
#pragma unroll
    for (int mb = 0; mb < 4; ++mb)
#pragma unroll
      for (int nb = 0; nb < 4; ++nb)
#pragma unroll
        for (int r = 0; r < 4; ++r)
          Ps[w][(mb * 16 + g * 4 + r) * 64 + nb * 16 + c15] = f2bf(s[mb][nb][r]);

    // O += P @ V
#pragma unroll
    for (int kc = 0; kc < 2; ++kc) {
      s16x8 pf[4], vf[4];
#pragma unroll
      for (int mb = 0; mb < 4; ++mb)
        pf[mb] = *(const s16x8*)&Ps[w][(mb * 16 + c15) * 64 + kc * 32 + g * 8];
#pragma unroll
      for (int db = 0; db < 4; ++db)
        vf[db] = *(const s16x8*)&Vt[(db * 16 + c15) * 64 + kc * 32 + g * 8];
#pragma unroll
      for (int mb = 0; mb < 4; ++mb)
#pragma unroll
        for (int db = 0; db < 4; ++db) o[mb][db] = mfma16(pf[mb], vf[db], o[mb][db]);
    }
    __syncthreads();  // protect Ks/Vt before next stage
  }

  // epilogue: O / l, write in torch-raw-reshape layout
#pragma unroll
  for (int mb = 0; mb < 4; ++mb)
#pragma unroll
    for (int db = 0; db < 4; ++db)
#pragma unroll
      for (int r = 0; r < 4; ++r) {
        int t = qb * 256 + w * 64 + mb * 16 + g * 4 + r;
        float val = o[mb][db][r] / lrow[mb][r];
        AO[(2 * h + b) * 131072 + t * 64 + db * 16 + c15] = f2bf(val);
      }
}

// ---------- launch ----------
extern "C" void kernel_launch(void* const* d_in, const int* in_sizes, int n_in,
                              void* d_out, int out_size, void* d_ws, size_t ws_size,
                              hipStream_t stream) {
  const float* x = (const float*)d_in[0];
  const float* Wq = (const float*)d_in[1];
  const float* Wk = (const float*)d_in[2];
  const float* Wv = (const float*)d_in[3];
  const float* Wp = (const float*)d_in[4];
  const float* bp = (const float*)d_in[5];
  float* out = (float*)d_out;

  u16* Xb = (u16*)d_ws;                   // [4096][1024]
  u16* Wt = Xb + 4096 * 1024;             // [3072][1024]
  u16* WpT = Wt + 3072 * 1024;            // [1024][1024]
  u16* QKV = WpT + 1024 * 1024;           // [4096][3072]
  u16* AO = QKV + 4096 * 3072;            // [4096][1024]

  k_cast_bf16<<<4096, 256, 0, stream>>>(x, Xb);
  k_wqkv<<<dim3(16, 48), 256, 0, stream>>>(Wq, Wk, Wv, Wt);
  k_wp<<<dim3(16, 16), 256, 0, stream>>>(Wp, WpT);
  gemm_bt<0><<<dim3(32 * 24), 256, 0, stream>>>(Xb, Wt, QKV, nullptr, nullptr, 4096, 3072, 1024);
  attn_fwd<<<dim3(8, 32), 256, 0, stream>>>(QKV, AO);
  gemm_bt<1><<<dim3(32 * 8), 256, 0, stream>>>(AO, WpT, nullptr, out, bp, 4096, 1024, 1024);
}

// Round 2
// 323.910 us; speedup vs baseline: 1.0720x; 1.0720x over previous
//
#include <hip/hip_runtime.h>

// ---------- types ----------
typedef unsigned short u16;
typedef __attribute__((ext_vector_type(4))) float f32x4;
typedef __attribute__((ext_vector_type(8))) short s16x8;
typedef __attribute__((ext_vector_type(8))) __bf16 bf16x8;
typedef __attribute__((ext_vector_type(4))) unsigned short u16x4;

#define LOG2E 1.44269504088896340736f

__device__ __forceinline__ u16 f2bf(float f) {
  unsigned u = __builtin_bit_cast(unsigned, f);
  u += 0x7fffu + ((u >> 16) & 1u);  // RNE
  return (u16)(u >> 16);
}

__device__ __forceinline__ f32x4 mfma16(s16x8 a, s16x8 b, f32x4 c) {
  return __builtin_amdgcn_mfma_f32_16x16x32_bf16(
      __builtin_bit_cast(bf16x8, a), __builtin_bit_cast(bf16x8, b), c, 0, 0, 0);
}

// XOR-swizzle mask for u16-indexed rows of 64 elems (128B): flips idx bits 3..5.
__device__ __forceinline__ int swzm(int row) {
  return (((row & 7) ^ ((row >> 3) & 7)) << 3);
}

// global -> LDS direct copy, 16B per lane. LDS dest must be uniform-base + lane*16.
#define GLOAD_LDS16(g, l)                                                      \
  __builtin_amdgcn_global_load_lds(                                            \
      (const __attribute__((address_space(1))) unsigned int*)(g),              \
      (__attribute__((address_space(3))) unsigned int*)(l), 16, 0, 0)

// ---------- cast x f32 -> bf16 (4 elems/thread, exact grid) ----------
__global__ __launch_bounds__(256) void k_cast_bf16(const float* __restrict__ in,
                                                   u16* __restrict__ out) {
  int i = (blockIdx.x * 256 + threadIdx.x) * 4;
  float4 v = *(const float4*)(in + i);
  u16x4 o = {f2bf(v.x), f2bf(v.y), f2bf(v.z), f2bf(v.w)};
  *(u16x4*)(out + i) = o;
}

// ---------- Wq/Wk/Wv [H,C,D] f32 -> Wt [3*H*D][C] bf16 (B^T layout) ----------
__global__ __launch_bounds__(256) void k_wqkv(const float* __restrict__ Wq,
                                              const float* __restrict__ Wk,
                                              const float* __restrict__ Wv,
                                              u16* __restrict__ Wt) {
  int z = blockIdx.y;  // 0..47
  int qkv = z >> 4, h = z & 15;
  const float* in = (qkv == 0 ? Wq : (qkv == 1 ? Wk : Wv)) + h * 1024 * 64;
  int c0 = blockIdx.x * 64;
  __shared__ float tile[64][65];
  int t = threadIdx.x;
  int rA = t >> 4, cA = (t & 15) * 4;
#pragma unroll
  for (int rr = 0; rr < 4; ++rr) {
    int c = rr * 16 + rA;
    float4 v = *(const float4*)(in + (c0 + c) * 64 + cA);
    tile[c][cA] = v.x; tile[c][cA + 1] = v.y; tile[c][cA + 2] = v.z; tile[c][cA + 3] = v.w;
  }
  __syncthreads();
  int obase = qkv * 1024 + h * 64;
#pragma unroll
  for (int rr = 0; rr < 4; ++rr) {
    int d = rr * 16 + rA;
    u16x4 o = {f2bf(tile[cA][d]), f2bf(tile[cA + 1][d]), f2bf(tile[cA + 2][d]),
               f2bf(tile[cA + 3][d])};
    *(u16x4*)(Wt + (obase + d) * 1024 + c0 + cA) = o;
  }
}

// ---------- Wp [1024][1024] f32 -> WpT [n][k] bf16 ----------
__global__ __launch_bounds__(256) void k_wp(const float* __restrict__ in,
                                            u16* __restrict__ out) {
  int r0 = blockIdx.y * 64, c0 = blockIdx.x * 64;
  __shared__ float tile[64][65];
  int t = threadIdx.x;
  int rA = t >> 4, cA = (t & 15) * 4;
#pragma unroll
  for (int rr = 0; rr < 4; ++rr) {
    int r = rr * 16 + rA;
    float4 v = *(const float4*)(in + (r0 + r) * 1024 + c0 + cA);
    tile[r][cA] = v.x; tile[r][cA + 1] = v.y; tile[r][cA + 2] = v.z; tile[r][cA + 3] = v.w;
  }
  __syncthreads();
#pragma unroll
  for (int rr = 0; rr < 4; ++rr) {
    int c = rr * 16 + rA;
    u16x4 o = {f2bf(tile[cA][c]), f2bf(tile[cA + 1][c]), f2bf(tile[cA + 2][c]),
               f2bf(tile[cA + 3][c])};
    *(u16x4*)(out + (c0 + c) * 1024 + r0 + cA) = o;
  }
}

// ---------- GEMM: C[M,N] = A[M,K] @ Bt[N,K]^T  (bf16 in, f32 acc) ----------
template <int F32OUT>
__global__ __launch_bounds__(256) void gemm_bt(const u16* __restrict__ A,
                                               const u16* __restrict__ Bt,
                                               u16* __restrict__ Cb,
                                               float* __restrict__ Cf,
                                               const float* __restrict__ bias,
                                               int M, int N, int K) {
  __shared__ alignas(16) u16 As[128 * 64];
  __shared__ alignas(16) u16 Bs[128 * 64];
  const int tid = threadIdx.x;
  const int lane = tid & 63, w = tid >> 6;
  const int wr = w >> 1, wc = w & 1;
  const int g = lane >> 4, c15 = lane & 15;
  const int nbk = N >> 7;
  const int bm = blockIdx.x / nbk, bn = blockIdx.x % nbk;

  f32x4 acc[4][4] = {};

  const int srow = tid >> 3;        // 0..31 (+ i*32)
  const int scol = (tid & 7) * 8;   // 0..56
  const u16* Ag = A + (bm * 128 + srow) * K + scol;
  const u16* Bg = Bt + (bn * 128 + srow) * K + scol;
  const int lds_e = tid * 8;        // + i*2048

  for (int kt = 0; kt < K; kt += 64) {
#pragma unroll
    for (int i = 0; i < 4; ++i) GLOAD_LDS16(Ag + i * 32 * K + kt, &As[lds_e + i * 2048]);
#pragma unroll
    for (int i = 0; i < 4; ++i) GLOAD_LDS16(Bg + i * 32 * K + kt, &Bs[lds_e + i * 2048]);
    __syncthreads();
#pragma unroll
    for (int kc = 0; kc < 2; ++kc) {
      s16x8 a[4], b[4];
#pragma unroll
      for (int mb = 0; mb < 4; ++mb)
        a[mb] = *(const s16x8*)&As[(wr * 64 + mb * 16 + c15) * 64 + kc * 32 + g * 8];
#pragma unroll
      for (int nb = 0; nb < 4; ++nb)
        b[nb] = *(const s16x8*)&Bs[(wc * 64 + nb * 16 + c15) * 64 + kc * 32 + g * 8];
#pragma unroll
      for (int mb = 0; mb < 4; ++mb)
#pragma unroll
        for (int nb = 0; nb < 4; ++nb) acc[mb][nb] = mfma16(a[mb], b[nb], acc[mb][nb]);
    }
    __syncthreads();
  }
#pragma unroll
  for (int mb = 0; mb < 4; ++mb) {
#pragma unroll
    for (int nb = 0; nb < 4; ++nb) {
      int row0 = bm * 128 + wr * 64 + mb * 16 + g * 4;
      int col = bn * 128 + wc * 64 + nb * 16 + c15;
#pragma unroll
      for (int r = 0; r < 4; ++r) {
        float v = acc[mb][nb][r];
        if (F32OUT)
          Cf[(row0 + r) * N + col] = v + bias[col];
        else
          Cb[(row0 + r) * N + col] = f2bf(v);
      }
    }
  }
}

// ---------- flash attention ----------
// QKV [4096][3072] bf16 (row = b*2048+t, col = qkv*1024 + h*64 + d)
// AO: torch-raw-reshape layout: AO[(2h+b)*131072 + t*64 + d]  (as [4096][1024])
// Grid: (16 q-blocks of 128 rows, 32 b*h). 4 waves/block, 32 q-rows/wave.
// Ks/Vt/Ps XOR-swizzled (bits 3..5 of within-row u16 offset) to kill bank conflicts.
__global__ __launch_bounds__(256, 2) void attn_fwd(const u16* __restrict__ QKV,
                                                   u16* __restrict__ AO) {
  __shared__ alignas(16) u16 Ks[64 * 64];      // [key][d] swizzled
  __shared__ alignas(16) u16 Vt[64 * 64];      // [d][key] swizzled
  __shared__ alignas(16) u16 Ps[4][32 * 64];   // per-wave P [q][key] swizzled
  const int tid = threadIdx.x, lane = tid & 63, w = tid >> 6;
  const int qb = blockIdx.x;       // 0..15
  const int bh = blockIdx.y;       // 0..31
  const int h = bh >> 1, b = bh & 1;
  const int g = lane >> 4, c15 = lane & 15;
  const int bt0 = b * 2048;
  const float CS = 0.125f * LOG2E;  // scale folded with log2e

  // Q fragments (stay in regs): rows qb*128 + w*32 + mb*16 + c15
  s16x8 q[2][2];
#pragma unroll
  for (int mb = 0; mb < 2; ++mb)
#pragma unroll
    for (int kc = 0; kc < 2; ++kc) {
      int row = bt0 + qb * 128 + w * 32 + mb * 16 + c15;
      q[mb][kc] = *(const s16x8*)&QKV[row * 3072 + h * 64 + kc * 32 + g * 8];
    }

  f32x4 o[2][4] = {};
  float mrow[2][4], lrow[2][4];
#pragma unroll
  for (int mb = 0; mb < 2; ++mb)
#pragma unroll
    for (int r = 0; r < 4; ++r) { mrow[mb][r] = -1e30f; lrow[mb][r] = 0.f; }

  const int skey = tid >> 3;        // 0..31 (+ i*32)
  const int schunk = tid & 7;       // 16B chunk index within 128B row
  const u16* Vg = QKV + (bt0 + skey) * 3072 + 2048 + h * 64 + schunk * 8;

  for (int key0 = 0; key0 < 2048; key0 += 64) {
    // stage K tile -> LDS direct; LDS dest linear, global chunk pre-permuted
    // so that LDS holds the swizzled layout (rule: both-sides-or-neither).
#pragma unroll
    for (int i = 0; i < 2; ++i) {
      int key = skey + i * 32;
      int s7 = (key & 7) ^ ((key >> 3) & 7);
      const u16* src =
          QKV + (bt0 + key0 + key) * 3072 + 1024 + h * 64 + ((schunk ^ s7) * 8);
      GLOAD_LDS16(src, &Ks[tid * 8 + i * 2048]);
    }
    // stage V tile transposed via registers, swizzled writes
#pragma unroll
    for (int i = 0; i < 2; ++i) {
      s16x8 v = *(const s16x8*)(Vg + (key0 + i * 32) * 3072);
      int key = skey + i * 32;
#pragma unroll
      for (int j = 0; j < 8; ++j) {
        int d = schunk * 8 + j;
        Vt[d * 64 + (key ^ swzm(d))] = (u16)v[j];
      }
    }
    __syncthreads();

    // S = Q K^T (pre-scaled by CS after MFMA)
    f32x4 s[2][4] = {};
#pragma unroll
    for (int kc = 0; kc < 2; ++kc) {
      s16x8 kf[4];
#pragma unroll
      for (int nb = 0; nb < 4; ++nb) {
        int row = nb * 16 + c15;
        kf[nb] = *(const s16x8*)&Ks[row * 64 + ((kc * 32 + g * 8) ^ swzm(row))];
      }
#pragma unroll
      for (int mb = 0; mb < 2; ++mb)
#pragma unroll
        for (int nb = 0; nb < 4; ++nb) s[mb][nb] = mfma16(q[mb][kc], kf[nb], s[mb][nb]);
    }

    // online softmax (rows on 16-lane groups), scaled (log2) domain
#pragma unroll
    for (int mb = 0; mb < 2; ++mb) {
#pragma unroll
      for (int r = 0; r < 4; ++r) {
        float mx = -1e30f;
#pragma unroll
        for (int nb = 0; nb < 4; ++nb) {
          float v = s[mb][nb][r] * CS;
          s[mb][nb][r] = v;
          mx = fmaxf(mx, v);
        }
#pragma unroll
        for (int off = 8; off >= 1; off >>= 1) mx = fmaxf(mx, __shfl_xor(mx, off, 64));
        float mo = mrow[mb][r];
        float mn = fmaxf(mo, mx);
        float alpha = exp2f(mo - mn);
        mrow[mb][r] = mn;
        float rs = 0.f;
#pragma unroll
        for (int nb = 0; nb < 4; ++nb) {
          float p = exp2f(s[mb][nb][r] - mn);
          s[mb][nb][r] = p;
          rs += p;
        }
#pragma unroll
        for (int off = 8; off >= 1; off >>= 1) rs += __shfl_xor(rs, off, 64);
        lrow[mb][r] = lrow[mb][r] * alpha + rs;
#pragma unroll
        for (int db = 0; db < 4; ++db) o[mb][db][r] *= alpha;
      }
    }

    // P -> per-wave LDS (bf16), swizzled
#pragma unroll
    for (int mb = 0; mb < 2; ++mb)
#pragma unroll
      for (int nb = 0; nb < 4; ++nb)
#pragma unroll
        for (int r = 0; r < 4; ++r) {
          int row = mb * 16 + g * 4 + r;
          Ps[w][row * 64 + ((nb * 16 + c15) ^ swzm(row))] = f2bf(s[mb][nb][r]);
        }

    // O += P @ V
#pragma unroll
    for (int kc = 0; kc < 2; ++kc) {
      s16x8 pf[2], vf[4];
#pragma unroll
      for (int mb = 0; mb < 2; ++mb) {
        int row = mb * 16 + c15;
        pf[mb] = *(const s16x8*)&Ps[w][row * 64 + ((kc * 32 + g * 8) ^ swzm(row))];
      }
#pragma unroll
      for (int db = 0; db < 4; ++db) {
        int row = db * 16 + c15;
        vf[db] = *(const s16x8*)&Vt[row * 64 + ((kc * 32 + g * 8) ^ swzm(row))];
      }
#pragma unroll
      for (int mb = 0; mb < 2; ++mb)
#pragma unroll
        for (int db = 0; db < 4; ++db) o[mb][db] = mfma16(pf[mb], vf[db], o[mb][db]);
    }
    __syncthreads();  // protect Ks/Vt/Ps before next stage
  }

  // epilogue: O / l, write in torch-raw-reshape layout
#pragma unroll
  for (int mb = 0; mb < 2; ++mb)
#pragma unroll
    for (int r = 0; r < 4; ++r) {
      float rinv = 1.0f / lrow[mb][r];
      int t = qb * 128 + w * 32 + mb * 16 + g * 4 + r;
#pragma unroll
      for (int db = 0; db < 4; ++db)
        AO[(2 * h + b) * 131072 + t * 64 + db * 16 + c15] = f2bf(o[mb][db][r] * rinv);
    }
}

// ---------- launch ----------
extern "C" void kernel_launch(void* const* d_in, const int* in_sizes, int n_in,
                              void* d_out, int out_size, void* d_ws, size_t ws_size,
                              hipStream_t stream) {
  const float* x = (const float*)d_in[0];
  const float* Wq = (const float*)d_in[1];
  const float* Wk = (const float*)d_in[2];
  const float* Wv = (const float*)d_in[3];
  const float* Wp = (const float*)d_in[4];
  const float* bp = (const float*)d_in[5];
  float* out = (float*)d_out;

  u16* Xb = (u16*)d_ws;                   // [4096][1024]
  u16* Wt = Xb + 4096 * 1024;             // [3072][1024]
  u16* WpT = Wt + 3072 * 1024;            // [1024][1024]
  u16* QKV = WpT + 1024 * 1024;           // [4096][3072]
  u16* AO = QKV + 4096 * 3072;            // [4096][1024]

  k_cast_bf16<<<4096, 256, 0, stream>>>(x, Xb);
  k_wqkv<<<dim3(16, 48), 256, 0, stream>>>(Wq, Wk, Wv, Wt);
  k_wp<<<dim3(16, 16), 256, 0, stream>>>(Wp, WpT);
  gemm_bt<0><<<dim3(32 * 24), 256, 0, stream>>>(Xb, Wt, QKV, nullptr, nullptr, 4096, 3072, 1024);
  attn_fwd<<<dim3(16, 32), 256, 0, stream>>>(QKV, AO);
  gemm_bt<1><<<dim3(32 * 8), 256, 0, stream>>>(AO, WpT, nullptr, out, bp, 4096, 1024, 1024);
}

// Round 3
// 288.956 us; speedup vs baseline: 1.2017x; 1.1210x over previous
//
#include <hip/hip_runtime.h>

// ---------- types ----------
typedef unsigned short u16;
typedef __attribute__((ext_vector_type(4))) float f32x4;
typedef __attribute__((ext_vector_type(8))) short s16x8;
typedef __attribute__((ext_vector_type(8))) __bf16 bf16x8;
typedef __attribute__((ext_vector_type(4))) unsigned short u16x4;

#define LOG2E 1.44269504088896340736f

__device__ __forceinline__ u16 f2bf(float f) {
  unsigned u = __builtin_bit_cast(unsigned, f);
  u += 0x7fffu + ((u >> 16) & 1u);  // RNE
  return (u16)(u >> 16);
}

__device__ __forceinline__ f32x4 mfma16(s16x8 a, s16x8 b, f32x4 c) {
  return __builtin_amdgcn_mfma_f32_16x16x32_bf16(
      __builtin_bit_cast(bf16x8, a), __builtin_bit_cast(bf16x8, b), c, 0, 0, 0);
}

// XOR-swizzle mask for u16-indexed rows of 64 elems (128B): flips idx bits 3..5.
__device__ __forceinline__ int swzm(int row) {
  return (((row & 7) ^ ((row >> 3) & 7)) << 3);
}

// global -> LDS direct copy, 16B per lane. LDS dest must be uniform-base + lane*16.
#define GLOAD_LDS16(g, l)                                                      \
  __builtin_amdgcn_global_load_lds(                                            \
      (const __attribute__((address_space(1))) unsigned int*)(g),              \
      (__attribute__((address_space(3))) unsigned int*)(l), 16, 0, 0)

// ---------- cast x f32 -> bf16 (4 elems/thread, exact grid) ----------
__global__ __launch_bounds__(256) void k_cast_bf16(const float* __restrict__ in,
                                                   u16* __restrict__ out) {
  int i = (blockIdx.x * 256 + threadIdx.x) * 4;
  float4 v = *(const float4*)(in + i);
  u16x4 o = {f2bf(v.x), f2bf(v.y), f2bf(v.z), f2bf(v.w)};
  *(u16x4*)(out + i) = o;
}

// ---------- Wq/Wk/Wv [H,C,D] f32 -> Wt [3*H*D][C] bf16 (B^T layout) ----------
__global__ __launch_bounds__(256) void k_wqkv(const float* __restrict__ Wq,
                                              const float* __restrict__ Wk,
                                              const float* __restrict__ Wv,
                                              u16* __restrict__ Wt) {
  int z = blockIdx.y;  // 0..47
  int qkv = z >> 4, h = z & 15;
  const float* in = (qkv == 0 ? Wq : (qkv == 1 ? Wk : Wv)) + h * 1024 * 64;
  int c0 = blockIdx.x * 64;
  __shared__ float tile[64][65];
  int t = threadIdx.x;
  int rA = t >> 4, cA = (t & 15) * 4;
#pragma unroll
  for (int rr = 0; rr < 4; ++rr) {
    int c = rr * 16 + rA;
    float4 v = *(const float4*)(in + (c0 + c) * 64 + cA);
    tile[c][cA] = v.x; tile[c][cA + 1] = v.y; tile[c][cA + 2] = v.z; tile[c][cA + 3] = v.w;
  }
  __syncthreads();
  int obase = qkv * 1024 + h * 64;
#pragma unroll
  for (int rr = 0; rr < 4; ++rr) {
    int d = rr * 16 + rA;
    u16x4 o = {f2bf(tile[cA][d]), f2bf(tile[cA + 1][d]), f2bf(tile[cA + 2][d]),
               f2bf(tile[cA + 3][d])};
    *(u16x4*)(Wt + (obase + d) * 1024 + c0 + cA) = o;
  }
}

// ---------- Wp [1024][1024] f32 -> WpT [n][k] bf16 ----------
__global__ __launch_bounds__(256) void k_wp(const float* __restrict__ in,
                                            u16* __restrict__ out) {
  int r0 = blockIdx.y * 64, c0 = blockIdx.x * 64;
  __shared__ float tile[64][65];
  int t = threadIdx.x;
  int rA = t >> 4, cA = (t & 15) * 4;
#pragma unroll
  for (int rr = 0; rr < 4; ++rr) {
    int r = rr * 16 + rA;
    float4 v = *(const float4*)(in + (r0 + r) * 1024 + c0 + cA);
    tile[r][cA] = v.x; tile[r][cA + 1] = v.y; tile[r][cA + 2] = v.z; tile[r][cA + 3] = v.w;
  }
  __syncthreads();
#pragma unroll
  for (int rr = 0; rr < 4; ++rr) {
    int c = rr * 16 + rA;
    u16x4 o = {f2bf(tile[cA][c]), f2bf(tile[cA + 1][c]), f2bf(tile[cA + 2][c]),
               f2bf(tile[cA + 3][c])};
    *(u16x4*)(out + (c0 + c) * 1024 + r0 + cA) = o;
  }
}

// ---------- GEMM: C[M,N] = A[M,K] @ Bt[N,K]^T  (bf16 in, f32 acc) ----------
template <int F32OUT>
__global__ __launch_bounds__(256) void gemm_bt(const u16* __restrict__ A,
                                               const u16* __restrict__ Bt,
                                               u16* __restrict__ Cb,
                                               float* __restrict__ Cf,
                                               const float* __restrict__ bias,
                                               int M, int N, int K) {
  __shared__ alignas(16) u16 As[128 * 64];
  __shared__ alignas(16) u16 Bs[128 * 64];
  const int tid = threadIdx.x;
  const int lane = tid & 63, w = tid >> 6;
  const int wr = w >> 1, wc = w & 1;
  const int g = lane >> 4, c15 = lane & 15;
  const int nbk = N >> 7;
  const int bm = blockIdx.x / nbk, bn = blockIdx.x % nbk;

  f32x4 acc[4][4] = {};

  const int srow = tid >> 3;        // 0..31 (+ i*32)
  const int scol = (tid & 7) * 8;   // 0..56
  const u16* Ag = A + (bm * 128 + srow) * K + scol;
  const u16* Bg = Bt + (bn * 128 + srow) * K + scol;
  const int lds_e = tid * 8;        // + i*2048

  for (int kt = 0; kt < K; kt += 64) {
#pragma unroll
    for (int i = 0; i < 4; ++i) GLOAD_LDS16(Ag + i * 32 * K + kt, &As[lds_e + i * 2048]);
#pragma unroll
    for (int i = 0; i < 4; ++i) GLOAD_LDS16(Bg + i * 32 * K + kt, &Bs[lds_e + i * 2048]);
    __syncthreads();
#pragma unroll
    for (int kc = 0; kc < 2; ++kc) {
      s16x8 a[4], b[4];
#pragma unroll
      for (int mb = 0; mb < 4; ++mb)
        a[mb] = *(const s16x8*)&As[(wr * 64 + mb * 16 + c15) * 64 + kc * 32 + g * 8];
#pragma unroll
      for (int nb = 0; nb < 4; ++nb)
        b[nb] = *(const s16x8*)&Bs[(wc * 64 + nb * 16 + c15) * 64 + kc * 32 + g * 8];
#pragma unroll
      for (int mb = 0; mb < 4; ++mb)
#pragma unroll
        for (int nb = 0; nb < 4; ++nb) acc[mb][nb] = mfma16(a[mb], b[nb], acc[mb][nb]);
    }
    __syncthreads();
  }
#pragma unroll
  for (int mb = 0; mb < 4; ++mb) {
#pragma unroll
    for (int nb = 0; nb < 4; ++nb) {
      int row0 = bm * 128 + wr * 64 + mb * 16 + g * 4;
      int col = bn * 128 + wc * 64 + nb * 16 + c15;
#pragma unroll
      for (int r = 0; r < 4; ++r) {
        float v = acc[mb][nb][r];
        if (F32OUT)
          Cf[(row0 + r) * N + col] = v + bias[col];
        else
          Cb[(row0 + r) * N + col] = f2bf(v);
      }
    }
  }
}

// ---------- flash attention (double-buffered, defer-rescale) ----------
// QKV [4096][3072] bf16 (row = b*2048+t, col = qkv*1024 + h*64 + d)
// AO: torch-raw-reshape layout: AO[(2h+b)*131072 + t*64 + d]  (as [4096][1024])
// Grid: (16 q-blocks of 128 rows, 32 b*h). 4 waves/block, 32 q-rows/wave.
// 2-phase pipeline: stage(t+1) issued before compute(t); V writes placed late
// (T14); single barrier per iter; Ks/Vt/Ps XOR-swizzled.
__global__ __launch_bounds__(256, 2) void attn_fwd(const u16* __restrict__ QKV,
                                                   u16* __restrict__ AO) {
  __shared__ alignas(16) u16 Ks[2][64 * 64];   // [key][d] swizzled
  __shared__ alignas(16) u16 Vt[2][64 * 64];   // [d][key] swizzled
  __shared__ alignas(16) u16 Ps[4][32 * 64];   // per-wave P [q][key] swizzled
  const int tid = threadIdx.x, lane = tid & 63, w = tid >> 6;
  const int qb = blockIdx.x;       // 0..15
  const int bh = blockIdx.y;       // 0..31
  const int h = bh >> 1, b = bh & 1;
  const int g = lane >> 4, c15 = lane & 15;
  const int bt0 = b * 2048;
  const float CS = 0.125f * LOG2E;  // scale folded with log2e

  // Q fragments (stay in regs): rows qb*128 + w*32 + mb*16 + c15
  s16x8 q[2][2];
#pragma unroll
  for (int mb = 0; mb < 2; ++mb)
#pragma unroll
    for (int kc = 0; kc < 2; ++kc) {
      int row = bt0 + qb * 128 + w * 32 + mb * 16 + c15;
      q[mb][kc] = *(const s16x8*)&QKV[row * 3072 + h * 64 + kc * 32 + g * 8];
    }

  f32x4 o[2][4] = {};
  float mrow[2][4], lrow[2][4];
#pragma unroll
  for (int mb = 0; mb < 2; ++mb)
#pragma unroll
    for (int r = 0; r < 4; ++r) { mrow[mb][r] = -1e30f; lrow[mb][r] = 0.f; }

  const int skey = tid >> 3;        // 0..31 (+ i*32)
  const int schunk = tid & 7;       // 16B chunk index within 128B row
  const u16* Vg = QKV + (bt0 + skey) * 3072 + 2048 + h * 64 + schunk * 8;

  // K stage: linear LDS dest, pre-swizzled global source (both-sides rule)
  auto stageK = [&](int key0, int buf) {
#pragma unroll
    for (int i = 0; i < 2; ++i) {
      int key = skey + i * 32;
      int s7 = (key & 7) ^ ((key >> 3) & 7);
      const u16* src =
          QKV + (bt0 + key0 + key) * 3072 + 1024 + h * 64 + ((schunk ^ s7) * 8);
      GLOAD_LDS16(src, &Ks[buf][tid * 8 + i * 2048]);
    }
  };
  auto writeV = [&](const s16x8* v, int buf) {
#pragma unroll
    for (int i = 0; i < 2; ++i) {
      int key = skey + i * 32;
#pragma unroll
      for (int j = 0; j < 8; ++j) {
        int d = schunk * 8 + j;
        Vt[buf][d * 64 + (key ^ swzm(d))] = (u16)v[i][j];
      }
    }
  };

  // prologue: stage tile 0 into buf 0
  {
    stageK(0, 0);
    s16x8 v0[2];
    v0[0] = *(const s16x8*)(Vg + 0 * 3072);
    v0[1] = *(const s16x8*)(Vg + 32 * 3072);
    writeV(v0, 0);
  }
  __syncthreads();

  for (int t = 0; t < 32; ++t) {
    const int c = t & 1;
    const int key0 = t * 64;
    const bool more = (t < 31);
    s16x8 vn[2];
    if (more) {
      stageK(key0 + 64, c ^ 1);
      vn[0] = *(const s16x8*)(Vg + (key0 + 64) * 3072);
      vn[1] = *(const s16x8*)(Vg + (key0 + 96) * 3072);
    }

    // S = Q K^T (log2-scaled after MFMA)
    f32x4 s[2][4] = {};
    __builtin_amdgcn_s_setprio(1);
#pragma unroll
    for (int kc = 0; kc < 2; ++kc) {
      s16x8 kf[4];
#pragma unroll
      for (int nb = 0; nb < 4; ++nb) {
        int row = nb * 16 + c15;
        kf[nb] = *(const s16x8*)&Ks[c][row * 64 + ((kc * 32 + g * 8) ^ swzm(row))];
      }
#pragma unroll
      for (int mb = 0; mb < 2; ++mb)
#pragma unroll
        for (int nb = 0; nb < 4; ++nb) s[mb][nb] = mfma16(q[mb][kc], kf[nb], s[mb][nb]);
    }
    __builtin_amdgcn_s_setprio(0);

    // pass 1: row maxes (batched shfl reduces), defer-rescale test
    float mx[2][4];
    bool exceed = false;
#pragma unroll
    for (int mb = 0; mb < 2; ++mb)
#pragma unroll
      for (int r = 0; r < 4; ++r) {
        float m0 = -1e30f;
#pragma unroll
        for (int nb = 0; nb < 4; ++nb) {
          float v = s[mb][nb][r] * CS;
          s[mb][nb][r] = v;
          m0 = fmaxf(m0, v);
        }
#pragma unroll
        for (int off = 8; off >= 1; off >>= 1) m0 = fmaxf(m0, __shfl_xor(m0, off, 64));
        mx[mb][r] = m0;
        exceed = exceed || (m0 > mrow[mb][r] + 8.0f);
      }
    if (__any(exceed)) {  // rescale (rare after warm-up)
#pragma unroll
      for (int mb = 0; mb < 2; ++mb)
#pragma unroll
        for (int r = 0; r < 4; ++r) {
          float mn = fmaxf(mrow[mb][r], mx[mb][r]);
          float alpha = exp2f(mrow[mb][r] - mn);
          mrow[mb][r] = mn;
          lrow[mb][r] *= alpha;
#pragma unroll
          for (int db = 0; db < 4; ++db) o[mb][db][r] *= alpha;
        }
    }
    // pass 2: exponentiate + row sums
#pragma unroll
    for (int mb = 0; mb < 2; ++mb)
#pragma unroll
      for (int r = 0; r < 4; ++r) {
        float rs = 0.f;
#pragma unroll
        for (int nb = 0; nb < 4; ++nb) {
          float p = exp2f(s[mb][nb][r] - mrow[mb][r]);
          s[mb][nb][r] = p;
          rs += p;
        }
#pragma unroll
        for (int off = 8; off >= 1; off >>= 1) rs += __shfl_xor(rs, off, 64);
        lrow[mb][r] += rs;
      }

    // P -> per-wave LDS (bf16), swizzled
#pragma unroll
    for (int mb = 0; mb < 2; ++mb)
#pragma unroll
      for (int nb = 0; nb < 4; ++nb)
#pragma unroll
        for (int r = 0; r < 4; ++r) {
          int row = mb * 16 + g * 4 + r;
          Ps[w][row * 64 + ((nb * 16 + c15) ^ swzm(row))] = f2bf(s[mb][nb][r]);
        }

    // O += P @ V
    __builtin_amdgcn_s_setprio(1);
#pragma unroll
    for (int kc = 0; kc < 2; ++kc) {
      s16x8 pf[2], vf[4];
#pragma unroll
      for (int mb = 0; mb < 2; ++mb) {
        int row = mb * 16 + c15;
        pf[mb] = *(const s16x8*)&Ps[w][row * 64 + ((kc * 32 + g * 8) ^ swzm(row))];
      }
#pragma unroll
      for (int db = 0; db < 4; ++db) {
        int row = db * 16 + c15;
        vf[db] = *(const s16x8*)&Vt[c][row * 64 + ((kc * 32 + g * 8) ^ swzm(row))];
      }
#pragma unroll
      for (int mb = 0; mb < 2; ++mb)
#pragma unroll
        for (int db = 0; db < 4; ++db) o[mb][db] = mfma16(pf[mb], vf[db], o[mb][db]);
    }
    __builtin_amdgcn_s_setprio(0);

    // T14 write-late: V(t+1) reg->LDS just before the barrier
    if (more) writeV(vn, c ^ 1);
    __syncthreads();  // publishes buf c^1 (K via vmcnt drain, V via lgkm drain)
  }

  // epilogue: O / l, write in torch-raw-reshape layout
#pragma unroll
  for (int mb = 0; mb < 2; ++mb)
#pragma unroll
    for (int r = 0; r < 4; ++r) {
      float rinv = 1.0f / lrow[mb][r];
      int t = qb * 128 + w * 32 + mb * 16 + g * 4 + r;
#pragma unroll
      for (int db = 0; db < 4; ++db)
        AO[(2 * h + b) * 131072 + t * 64 + db * 16 + c15] = f2bf(o[mb][db][r] * rinv);
    }
}

// ---------- launch ----------
extern "C" void kernel_launch(void* const* d_in, const int* in_sizes, int n_in,
                              void* d_out, int out_size, void* d_ws, size_t ws_size,
                              hipStream_t stream) {
  const float* x = (const float*)d_in[0];
  const float* Wq = (const float*)d_in[1];
  const float* Wk = (const float*)d_in[2];
  const float* Wv = (const float*)d_in[3];
  const float* Wp = (const float*)d_in[4];
  const float* bp = (const float*)d_in[5];
  float* out = (float*)d_out;

  u16* Xb = (u16*)d_ws;                   // [4096][1024]
  u16* Wt = Xb + 4096 * 1024;             // [3072][1024]
  u16* WpT = Wt + 3072 * 1024;            // [1024][1024]
  u16* QKV = WpT + 1024 * 1024;           // [4096][3072]
  u16* AO = QKV + 4096 * 3072;            // [4096][1024]

  k_cast_bf16<<<4096, 256, 0, stream>>>(x, Xb);
  k_wqkv<<<dim3(16, 48), 256, 0, stream>>>(Wq, Wk, Wv, Wt);
  k_wp<<<dim3(16, 16), 256, 0, stream>>>(Wp, WpT);
  gemm_bt<0><<<dim3(32 * 24), 256, 0, stream>>>(Xb, Wt, QKV, nullptr, nullptr, 4096, 3072, 1024);
  attn_fwd<<<dim3(16, 32), 256, 0, stream>>>(QKV, AO);
  gemm_bt<1><<<dim3(32 * 8), 256, 0, stream>>>(AO, WpT, nullptr, out, bp, 4096, 1024, 1024);
}

// Round 4
// 251.142 us; speedup vs baseline: 1.3826x; 1.1506x over previous
//
#include <hip/hip_runtime.h>

// ---------- types ----------
typedef unsigned short u16;
typedef __attribute__((ext_vector_type(4))) float f32x4;
typedef __attribute__((ext_vector_type(8))) short s16x8;
typedef __attribute__((ext_vector_type(8))) __bf16 bf16x8;
typedef __attribute__((ext_vector_type(4))) unsigned short u16x4;

#define LOG2E 1.44269504088896340736f

__device__ __forceinline__ u16 f2bf(float f) {
  unsigned u = __builtin_bit_cast(unsigned, f);
  u += 0x7fffu + ((u >> 16) & 1u);  // RNE
  return (u16)(u >> 16);
}

__device__ __forceinline__ f32x4 mfma16(s16x8 a, s16x8 b, f32x4 c) {
  return __builtin_amdgcn_mfma_f32_16x16x32_bf16(
      __builtin_bit_cast(bf16x8, a), __builtin_bit_cast(bf16x8, b), c, 0, 0, 0);
}

// XOR-swizzle mask for u16-indexed rows of 64 elems (128B): flips idx bits 3..5.
__device__ __forceinline__ int swzm(int row) {
  return (((row & 7) ^ ((row >> 3) & 7)) << 3);
}

// global -> LDS direct copy, 16B per lane. LDS dest must be uniform-base + lane*16.
#define GLOAD_LDS16(g, l)                                                      \
  __builtin_amdgcn_global_load_lds(                                            \
      (const __attribute__((address_space(1))) unsigned int*)(g),              \
      (__attribute__((address_space(3))) unsigned int*)(l), 16, 0, 0)

// ---------- cast x f32 -> bf16 (4 elems/thread, exact grid) ----------
__global__ __launch_bounds__(256) void k_cast_bf16(const float* __restrict__ in,
                                                   u16* __restrict__ out) {
  int i = (blockIdx.x * 256 + threadIdx.x) * 4;
  float4 v = *(const float4*)(in + i);
  u16x4 o = {f2bf(v.x), f2bf(v.y), f2bf(v.z), f2bf(v.w)};
  *(u16x4*)(out + i) = o;
}

// ---------- Wq/Wk/Wv [H,C,D] f32 -> Wt [3*H*D][C] bf16 (B^T layout) ----------
__global__ __launch_bounds__(256) void k_wqkv(const float* __restrict__ Wq,
                                              const float* __restrict__ Wk,
                                              const float* __restrict__ Wv,
                                              u16* __restrict__ Wt) {
  int z = blockIdx.y;  // 0..47
  int qkv = z >> 4, h = z & 15;
  const float* in = (qkv == 0 ? Wq : (qkv == 1 ? Wk : Wv)) + h * 1024 * 64;
  int c0 = blockIdx.x * 64;
  __shared__ float tile[64][65];
  int t = threadIdx.x;
  int rA = t >> 4, cA = (t & 15) * 4;
#pragma unroll
  for (int rr = 0; rr < 4; ++rr) {
    int c = rr * 16 + rA;
    float4 v = *(const float4*)(in + (c0 + c) * 64 + cA);
    tile[c][cA] = v.x; tile[c][cA + 1] = v.y; tile[c][cA + 2] = v.z; tile[c][cA + 3] = v.w;
  }
  __syncthreads();
  int obase = qkv * 1024 + h * 64;
#pragma unroll
  for (int rr = 0; rr < 4; ++rr) {
    int d = rr * 16 + rA;
    u16x4 o = {f2bf(tile[cA][d]), f2bf(tile[cA + 1][d]), f2bf(tile[cA + 2][d]),
               f2bf(tile[cA + 3][d])};
    *(u16x4*)(Wt + (obase + d) * 1024 + c0 + cA) = o;
  }
}

// ---------- Wp [1024][1024] f32 -> WpT [n][k] bf16 ----------
__global__ __launch_bounds__(256) void k_wp(const float* __restrict__ in,
                                            u16* __restrict__ out) {
  int r0 = blockIdx.y * 64, c0 = blockIdx.x * 64;
  __shared__ float tile[64][65];
  int t = threadIdx.x;
  int rA = t >> 4, cA = (t & 15) * 4;
#pragma unroll
  for (int rr = 0; rr < 4; ++rr) {
    int r = rr * 16 + rA;
    float4 v = *(const float4*)(in + (r0 + r) * 1024 + c0 + cA);
    tile[r][cA] = v.x; tile[r][cA + 1] = v.y; tile[r][cA + 2] = v.z; tile[r][cA + 3] = v.w;
  }
  __syncthreads();
#pragma unroll
  for (int rr = 0; rr < 4; ++rr) {
    int c = rr * 16 + rA;
    u16x4 o = {f2bf(tile[cA][c]), f2bf(tile[cA + 1][c]), f2bf(tile[cA + 2][c]),
               f2bf(tile[cA + 3][c])};
    *(u16x4*)(out + (c0 + c) * 1024 + r0 + cA) = o;
  }
}

// ---------- GEMM: C[M,N] = A[M,K] @ Bt[N,K]^T  (bf16 in, f32 acc) ----------
template <int F32OUT>
__global__ __launch_bounds__(256) void gemm_bt(const u16* __restrict__ A,
                                               const u16* __restrict__ Bt,
                                               u16* __restrict__ Cb,
                                               float* __restrict__ Cf,
                                               const float* __restrict__ bias,
                                               int M, int N, int K) {
  __shared__ alignas(16) u16 As[128 * 64];
  __shared__ alignas(16) u16 Bs[128 * 64];
  const int tid = threadIdx.x;
  const int lane = tid & 63, w = tid >> 6;
  const int wr = w >> 1, wc = w & 1;
  const int g = lane >> 4, c15 = lane & 15;
  const int nbk = N >> 7;
  const int bm = blockIdx.x / nbk, bn = blockIdx.x % nbk;

  f32x4 acc[4][4] = {};

  const int srow = tid >> 3;        // 0..31 (+ i*32)
  const int scol = (tid & 7) * 8;   // 0..56
  const u16* Ag = A + (bm * 128 + srow) * K + scol;
  const u16* Bg = Bt + (bn * 128 + srow) * K + scol;
  const int lds_e = tid * 8;        // + i*2048

  for (int kt = 0; kt < K; kt += 64) {
#pragma unroll
    for (int i = 0; i < 4; ++i) GLOAD_LDS16(Ag + i * 32 * K + kt, &As[lds_e + i * 2048]);
#pragma unroll
    for (int i = 0; i < 4; ++i) GLOAD_LDS16(Bg + i * 32 * K + kt, &Bs[lds_e + i * 2048]);
    __syncthreads();
#pragma unroll
    for (int kc = 0; kc < 2; ++kc) {
      s16x8 a[4], b[4];
#pragma unroll
      for (int mb = 0; mb < 4; ++mb)
        a[mb] = *(const s16x8*)&As[(wr * 64 + mb * 16 + c15) * 64 + kc * 32 + g * 8];
#pragma unroll
      for (int nb = 0; nb < 4; ++nb)
        b[nb] = *(const s16x8*)&Bs[(wc * 64 + nb * 16 + c15) * 64 + kc * 32 + g * 8];
#pragma unroll
      for (int mb = 0; mb < 4; ++mb)
#pragma unroll
        for (int nb = 0; nb < 4; ++nb) acc[mb][nb] = mfma16(a[mb], b[nb], acc[mb][nb]);
    }
    __syncthreads();
  }
#pragma unroll
  for (int mb = 0; mb < 4; ++mb) {
#pragma unroll
    for (int nb = 0; nb < 4; ++nb) {
      int row0 = bm * 128 + wr * 64 + mb * 16 + g * 4;
      int col = bn * 128 + wc * 64 + nb * 16 + c15;
#pragma unroll
      for (int r = 0; r < 4; ++r) {
        float v = acc[mb][nb][r];
        if (F32OUT)
          Cf[(row0 + r) * N + col] = v + bias[col];
        else
          Cb[(row0 + r) * N + col] = f2bf(v);
      }
    }
  }
}

// ---------- flash attention (dbuf + swapped QK^T + defer-rescale) ----------
// QKV [4096][3072] bf16 (row = b*2048+t, col = qkv*1024 + h*64 + d)
// AO: torch-raw-reshape layout: AO[(2h+b)*131072 + t*64 + d]  (as [4096][1024])
// Grid: (16 q-blocks of 128 rows, 32 b*h). 4 waves/block, 32 q-rows/wave.
// Swapped QK^T: S^T = mfma(K, Q) with the SAME fragments -> lane holds 16 keys
// of ONE q-row (q = c15): row-reduce = 15 in-reg ops + 2 shfl_xor; P written as
// 8 ds_write_b64 instead of 32 scalars. PV unswapped (o rows = q = g*4+r);
// lrow/alpha broadcast c15-domain -> row-domain via 8 bpermutes (epilogue /
// rare rescale only).
__global__ __launch_bounds__(256, 2) void attn_fwd(const u16* __restrict__ QKV,
                                                   u16* __restrict__ AO) {
  __shared__ alignas(16) u16 Ks[2][64 * 64];   // [key][d] swizzled
  __shared__ alignas(16) u16 Vt[2][64 * 64];   // [d][key] swizzled
  __shared__ alignas(16) u16 Ps[4][32 * 64];   // per-wave P [q][key] swizzled
  const int tid = threadIdx.x, lane = tid & 63, w = tid >> 6;
  const int qb = blockIdx.x;       // 0..15
  const int bh = blockIdx.y;       // 0..31
  const int h = bh >> 1, b = bh & 1;
  const int g = lane >> 4, c15 = lane & 15;
  const int bt0 = b * 2048;
  const float CS = 0.125f * LOG2E;  // scale folded with log2e

  // Q fragments (stay in regs): rows qb*128 + w*32 + mb*16 + c15
  s16x8 q[2][2];
#pragma unroll
  for (int mb = 0; mb < 2; ++mb)
#pragma unroll
    for (int kc = 0; kc < 2; ++kc) {
      int row = bt0 + qb * 128 + w * 32 + mb * 16 + c15;
      q[mb][kc] = *(const s16x8*)&QKV[row * 3072 + h * 64 + kc * 32 + g * 8];
    }

  f32x4 o[2][4] = {};
  float mrow[2], lrow[2];  // per-lane: q = mb*16 + c15 (replicated across groups)
#pragma unroll
  for (int mb = 0; mb < 2; ++mb) { mrow[mb] = -1e30f; lrow[mb] = 0.f; }

  const int skey = tid >> 3;        // 0..31 (+ i*32)
  const int schunk = tid & 7;       // 16B chunk index within 128B row
  const u16* Vg = QKV + (bt0 + skey) * 3072 + 2048 + h * 64 + schunk * 8;

  // K stage: linear LDS dest, pre-swizzled global source (both-sides rule)
  auto stageK = [&](int key0, int buf) {
#pragma unroll
    for (int i = 0; i < 2; ++i) {
      int key = skey + i * 32;
      int s7 = (key & 7) ^ ((key >> 3) & 7);
      const u16* src =
          QKV + (bt0 + key0 + key) * 3072 + 1024 + h * 64 + ((schunk ^ s7) * 8);
      GLOAD_LDS16(src, &Ks[buf][tid * 8 + i * 2048]);
    }
  };
  auto writeV = [&](const s16x8* v, int buf) {
#pragma unroll
    for (int i = 0; i < 2; ++i) {
      int key = skey + i * 32;
#pragma unroll
      for (int j = 0; j < 8; ++j) {
        int d = schunk * 8 + j;
        Vt[buf][d * 64 + (key ^ swzm(d))] = (u16)v[i][j];
      }
    }
  };

  // prologue: stage tile 0 into buf 0
  {
    stageK(0, 0);
    s16x8 v0[2];
    v0[0] = *(const s16x8*)(Vg + 0 * 3072);
    v0[1] = *(const s16x8*)(Vg + 32 * 3072);
    writeV(v0, 0);
  }
  __syncthreads();

  for (int t = 0; t < 32; ++t) {
    const int c = t & 1;
    const int key0 = t * 64;
    const bool more = (t < 31);
    s16x8 vn[2];
    if (more) {
      stageK(key0 + 64, c ^ 1);
      vn[0] = *(const s16x8*)(Vg + (key0 + 64) * 3072);
      vn[1] = *(const s16x8*)(Vg + (key0 + 96) * 3072);
    }

    // S^T = K Q^T: s[mb][nb] lane holds S[key=nb*16+g*4+r][q=mb*16+c15]
    f32x4 s[2][4] = {};
    __builtin_amdgcn_s_setprio(1);
#pragma unroll
    for (int kc = 0; kc < 2; ++kc) {
      s16x8 kf[4];
#pragma unroll
      for (int nb = 0; nb < 4; ++nb) {
        int row = nb * 16 + c15;
        kf[nb] = *(const s16x8*)&Ks[c][row * 64 + ((kc * 32 + g * 8) ^ swzm(row))];
      }
#pragma unroll
      for (int mb = 0; mb < 2; ++mb)
#pragma unroll
        for (int nb = 0; nb < 4; ++nb) s[mb][nb] = mfma16(kf[nb], q[mb][kc], s[mb][nb]);
    }
    __builtin_amdgcn_s_setprio(0);

    // softmax: per lane one q-row, 16 in-lane keys + cross-group (2 shfl)
    float mx[2];
    bool exceed = false;
#pragma unroll
    for (int mb = 0; mb < 2; ++mb) {
#pragma unroll
      for (int nb = 0; nb < 4; ++nb)
#pragma unroll
        for (int r = 0; r < 4; ++r) s[mb][nb][r] *= CS;
      float m01 = fmaxf(fmaxf(s[mb][0][0], s[mb][0][1]), fmaxf(s[mb][0][2], s[mb][0][3]));
      float m11 = fmaxf(fmaxf(s[mb][1][0], s[mb][1][1]), fmaxf(s[mb][1][2], s[mb][1][3]));
      float m21 = fmaxf(fmaxf(s[mb][2][0], s[mb][2][1]), fmaxf(s[mb][2][2], s[mb][2][3]));
      float m31 = fmaxf(fmaxf(s[mb][3][0], s[mb][3][1]), fmaxf(s[mb][3][2], s[mb][3][3]));
      float m0 = fmaxf(fmaxf(m01, m11), fmaxf(m21, m31));
      m0 = fmaxf(m0, __shfl_xor(m0, 16, 64));
      m0 = fmaxf(m0, __shfl_xor(m0, 32, 64));
      mx[mb] = m0;
      exceed = exceed || (m0 > mrow[mb] + 8.0f);
    }
    if (__any(exceed)) {  // rescale (rare after warm-up)
#pragma unroll
      for (int mb = 0; mb < 2; ++mb) {
        float mn = fmaxf(mrow[mb], mx[mb]);
        float alpha = exp2f(mrow[mb] - mn);
        mrow[mb] = mn;
        lrow[mb] *= alpha;
#pragma unroll
        for (int r = 0; r < 4; ++r) {
          float aB = __shfl(alpha, g * 4 + r, 64);  // c15-domain -> row-domain
#pragma unroll
          for (int db = 0; db < 4; ++db) o[mb][db][r] *= aB;
        }
      }
    }
#pragma unroll
    for (int mb = 0; mb < 2; ++mb) {
      float m = mrow[mb];
#pragma unroll
      for (int nb = 0; nb < 4; ++nb)
#pragma unroll
        for (int r = 0; r < 4; ++r) s[mb][nb][r] = exp2f(s[mb][nb][r] - m);
      float s0 = (s[mb][0][0] + s[mb][0][1]) + (s[mb][0][2] + s[mb][0][3]);
      float s1 = (s[mb][1][0] + s[mb][1][1]) + (s[mb][1][2] + s[mb][1][3]);
      float s2 = (s[mb][2][0] + s[mb][2][1]) + (s[mb][2][2] + s[mb][2][3]);
      float s3 = (s[mb][3][0] + s[mb][3][1]) + (s[mb][3][2] + s[mb][3][3]);
      float rs = (s0 + s1) + (s2 + s3);
      rs += __shfl_xor(rs, 16, 64);
      rs += __shfl_xor(rs, 32, 64);
      lrow[mb] += rs;
      // P write: 4 consecutive keys (r=0..3) -> one b64 per (mb,nb)
      int row = mb * 16 + c15;
#pragma unroll
      for (int nb = 0; nb < 4; ++nb) {
        u16x4 pk = {f2bf(s[mb][nb][0]), f2bf(s[mb][nb][1]), f2bf(s[mb][nb][2]),
                    f2bf(s[mb][nb][3])};
        *(u16x4*)&Ps[w][row * 64 + ((nb * 16 + g * 4) ^ swzm(row))] = pk;
      }
    }

    // O += P @ V (unswapped; o rows = q = g*4+r, cols = d = db*16+c15)
    __builtin_amdgcn_s_setprio(1);
#pragma unroll
    for (int kc = 0; kc < 2; ++kc) {
      s16x8 pf[2], vf[4];
#pragma unroll
      for (int mb = 0; mb < 2; ++mb) {
        int row = mb * 16 + c15;
        pf[mb] = *(const s16x8*)&Ps[w][row * 64 + ((kc * 32 + g * 8) ^ swzm(row))];
      }
#pragma unroll
      for (int db = 0; db < 4; ++db) {
        int row = db * 16 + c15;
        vf[db] = *(const s16x8*)&Vt[c][row * 64 + ((kc * 32 + g * 8) ^ swzm(row))];
      }
#pragma unroll
      for (int mb = 0; mb < 2; ++mb)
#pragma unroll
        for (int db = 0; db < 4; ++db) o[mb][db] = mfma16(pf[mb], vf[db], o[mb][db]);
    }
    __builtin_amdgcn_s_setprio(0);

    // T14 write-late: V(t+1) reg->LDS just before the barrier
    if (more) writeV(vn, c ^ 1);
    __syncthreads();  // publishes buf c^1 (K via vmcnt drain, V via lgkm drain)
  }

  // epilogue: O / l (broadcast lrow c15-domain -> row-domain), torch-raw layout
#pragma unroll
  for (int mb = 0; mb < 2; ++mb)
#pragma unroll
    for (int r = 0; r < 4; ++r) {
      float lB = __shfl(lrow[mb], g * 4 + r, 64);
      float rinv = 1.0f / lB;
      int trow = qb * 128 + w * 32 + mb * 16 + g * 4 + r;
#pragma unroll
      for (int db = 0; db < 4; ++db)
        AO[(2 * h + b) * 131072 + trow * 64 + db * 16 + c15] = f2bf(o[mb][db][r] * rinv);
    }
}

// ---------- launch ----------
extern "C" void kernel_launch(void* const* d_in, const int* in_sizes, int n_in,
                              void* d_out, int out_size, void* d_ws, size_t ws_size,
                              hipStream_t stream) {
  const float* x = (const float*)d_in[0];
  const float* Wq = (const float*)d_in[1];
  const float* Wk = (const float*)d_in[2];
  const float* Wv = (const float*)d_in[3];
  const float* Wp = (const float*)d_in[4];
  const float* bp = (const float*)d_in[5];
  float* out = (float*)d_out;

  u16* Xb = (u16*)d_ws;                   // [4096][1024]
  u16* Wt = Xb + 4096 * 1024;             // [3072][1024]
  u16* WpT = Wt + 3072 * 1024;            // [1024][1024]
  u16* QKV = WpT + 1024 * 1024;           // [4096][3072]
  u16* AO = QKV + 4096 * 3072;            // [4096][1024]

  k_cast_bf16<<<4096, 256, 0, stream>>>(x, Xb);
  k_wqkv<<<dim3(16, 48), 256, 0, stream>>>(Wq, Wk, Wv, Wt);
  k_wp<<<dim3(16, 16), 256, 0, stream>>>(Wp, WpT);
  gemm_bt<0><<<dim3(32 * 24), 256, 0, stream>>>(Xb, Wt, QKV, nullptr, nullptr, 4096, 3072, 1024);
  attn_fwd<<<dim3(16, 32), 256, 0, stream>>>(QKV, AO);
  gemm_bt<1><<<dim3(32 * 8), 256, 0, stream>>>(AO, WpT, nullptr, out, bp, 4096, 1024, 1024);
}